// Round 14
// baseline (566.918 us; speedup 1.0000x reference)
//
#include <hip/hip_runtime.h>

#define B_ 8
#define T_ 2048
#define C_ 768
#define H_ 3072
#define BT_ (B_ * T_)
#define BC_ (B_ * C_)
#define WSEG 128
#define NWSEG 16
#define LSEG 128
#define NLSEG 16
#define LWARM 96

typedef unsigned short u16;
typedef short bf16x8 __attribute__((ext_vector_type(8)));
typedef float f32x4 __attribute__((ext_vector_type(4)));

__device__ __forceinline__ float b2f(u16 u) {
    union { unsigned i; float f; } w; w.i = ((unsigned)u) << 16; return w.f;
}
__device__ __forceinline__ u16 f2b(float f) {
    union { float f; unsigned i; } w; w.f = f;
    return (u16)((w.i + 0x7fffu + ((w.i >> 16) & 1u)) >> 16);
}

typedef __attribute__((address_space(3))) unsigned int lds_u32;
typedef const __attribute__((address_space(1))) unsigned int glb_u32;
__device__ __forceinline__ void gld_lds16(const void* g, void* l) {
    __builtin_amdgcn_global_load_lds((glb_u32*)g, (lds_u32*)l, 16, 0, 0);
}

// ------------------------------------------------ LayerNorm + token-shift mix (f32 in, bf16 out)
template<int NOUT>
__global__ void lnmix(const float* __restrict__ x, const float* __restrict__ w,
                      const float* __restrict__ b,
                      const float* __restrict__ m1, const float* __restrict__ m2,
                      const float* __restrict__ m3,
                      u16* __restrict__ o1, u16* __restrict__ o2, u16* __restrict__ o3) {
    int row = blockIdx.x;
    int t = row % T_;
    const float* xr = x + (size_t)row * C_;
    const float* xp = xr - C_;
    int tid = threadIdx.x;
    float s = 0.f, s2 = 0.f, ps = 0.f, ps2 = 0.f;
    for (int i = tid; i < C_; i += 256) {
        float v = xr[i]; s += v; s2 += v * v;
        if (t > 0) { float u = xp[i]; ps += u; ps2 += u * u; }
    }
    for (int off = 32; off > 0; off >>= 1) {
        s += __shfl_down(s, off);  s2 += __shfl_down(s2, off);
        ps += __shfl_down(ps, off); ps2 += __shfl_down(ps2, off);
    }
    __shared__ float red[4][4];
    int wid = tid >> 6, lane = tid & 63;
    if (lane == 0) { red[wid][0] = s; red[wid][1] = s2; red[wid][2] = ps; red[wid][3] = ps2; }
    __syncthreads();
    if (tid == 0) {
        float a0 = 0, a1 = 0, a2 = 0, a3 = 0;
        for (int i = 0; i < 4; ++i) { a0 += red[i][0]; a1 += red[i][1]; a2 += red[i][2]; a3 += red[i][3]; }
        red[0][0] = a0; red[0][1] = a1; red[0][2] = a2; red[0][3] = a3;
    }
    __syncthreads();
    float mu = red[0][0] * (1.f / C_);
    float rs = rsqrtf(red[0][1] * (1.f / C_) - mu * mu + 1e-5f);
    float pmu = red[0][2] * (1.f / C_);
    float prs = rsqrtf(red[0][3] * (1.f / C_) - pmu * pmu + 1e-5f);
    size_t ob = (size_t)row * C_;
    for (int i = tid; i < C_; i += 256) {
        float wi = w[i], bi = b[i];
        float n = (xr[i] - mu) * rs * wi + bi;
        float np = (t > 0) ? (xp[i] - pmu) * prs * wi + bi : 0.f;
        o1[ob + i] = f2b(fmaf(m1[i], n - np, np));
        o2[ob + i] = f2b(fmaf(m2[i], n - np, np));
        if constexpr (NOUT == 3) o3[ob + i] = f2b(fmaf(m3[i], n - np, np));
    }
}

// ------------------------------------------------ batched transpose-cast f32[R][N] -> bf16[N][R]
struct TCJ { const float* s; u16* d; int R, Ncol, nbx, b0; };
struct TC7 { TCJ j[7]; };
__global__ void tcast_all(TC7 jobs) {
    __shared__ float t[32][33];
    int bid = blockIdx.x;
    int ji = 0;
#pragma unroll
    for (int k = 1; k < 7; ++k) if (bid >= jobs.j[k].b0) ji = k;
    TCJ jb = jobs.j[ji];
    int local = bid - jb.b0;
    int bx = local % jb.nbx, by = local / jb.nbx;
    int c0 = bx * 32, r0 = by * 32;
    int col = threadIdx.x & 31, rw = threadIdx.x >> 5;
#pragma unroll
    for (int i = 0; i < 4; ++i) {
        int r = rw + i * 8;
        t[r][col] = jb.s[(size_t)(r0 + r) * jb.Ncol + c0 + col];
    }
    __syncthreads();
#pragma unroll
    for (int i = 0; i < 4; ++i) {
        int r = rw + i * 8;
        jb.d[(size_t)(c0 + r) * jb.R + r0 + col] = f2b(t[col][r]);
    }
}

// ------------------------------------------------ 256x256 GEMM core, m201 8-phase schedule.
// 8 waves (2Mx4N, per-wave 128x64), BK=64, LDS = 2dbuf x 2half x 128x64 x {A,B} x 2B = 128KB.
// Per 2 K-tiles: 8 phases, each {frag ds_reads; stage 1 half-tile (2 gld_lds); barrier;
// lgkm(0); setprio+16 MFMA; barrier}. vmcnt(6) only at phases 4/8 (3 half-tiles in flight).
__device__ __forceinline__ void gemm_core256(const u16* __restrict__ A,
                                             const u16* __restrict__ WT,
                                             int K, int m0, int n0,
                                             u16* L, f32x4 acc[8][4]) {
    const int tid = threadIdx.x;
    const int lane = tid & 63, wid = tid >> 6;
    const int wr = wid >> 2, wc = wid & 3;
    const int r16 = lane & 15, g = lane >> 4;

    const int srow = tid >> 3;                 // 0..63
    const int sunit = tid & 7;
    const u16* pa = A + (size_t)(m0 + srow) * K + ((sunit ^ (srow & 7)) << 3);
    const u16* pb = WT + (size_t)(n0 + srow) * K + ((sunit ^ (srow & 7)) << 3);
    u16* lbase = L + tid * 8;

#define STG_A(d, h) do { \
        const u16* gp = pa + (size_t)((h) ? 128 : 0) * K; \
        u16* lp = lbase + ((d) * 2 + (h)) * 8192; \
        gld_lds16(gp, lp); gld_lds16(gp + (size_t)64 * K, lp + 4096); } while (0)
#define STG_B(d, h) do { \
        const u16* gp = pb + (size_t)((h) ? 128 : 0) * K; \
        u16* lp = lbase + 32768 + ((d) * 2 + (h)) * 8192; \
        gld_lds16(gp, lp); gld_lds16(gp + (size_t)64 * K, lp + 4096); } while (0)

    int offA[8], offB[4];
#pragma unroll
    for (int m = 0; m < 8; ++m) {
        int lr = m * 16 + r16;
        offA[m] = wr * 8192 + lr * 64 + ((g ^ (lr & 7)) << 3);
    }
#pragma unroll
    for (int n = 0; n < 4; ++n) {
        int lrb = (wc & 1) * 64 + n * 16 + r16;
        offB[n] = 32768 + (wc >> 1) * 8192 + lrb * 64 + ((g ^ (lrb & 7)) << 3);
    }

    bf16x8 aq[4][2], bq[2][2];

#define RD_A(QM, DOFF) do { _Pragma("unroll") \
        for (int mm = 0; mm < 4; ++mm) { \
            int o = offA[(QM) * 4 + mm] + (DOFF); \
            aq[mm][0] = *(const bf16x8*)(L + o); \
            aq[mm][1] = *(const bf16x8*)(L + (o ^ 32)); } } while (0)
#define RD_B(QN, DOFF) do { _Pragma("unroll") \
        for (int nn = 0; nn < 2; ++nn) { \
            int o = offB[(QN) * 2 + nn] + (DOFF); \
            bq[nn][0] = *(const bf16x8*)(L + o); \
            bq[nn][1] = *(const bf16x8*)(L + (o ^ 32)); } } while (0)
#define MM16(QM, QN) do { _Pragma("unroll") \
        for (int mm = 0; mm < 4; ++mm) { _Pragma("unroll") \
            for (int nn = 0; nn < 2; ++nn) { \
                acc[(QM)*4+mm][(QN)*2+nn] = __builtin_amdgcn_mfma_f32_16x16x32_bf16(aq[mm][0], bq[nn][0], acc[(QM)*4+mm][(QN)*2+nn], 0, 0, 0); \
                acc[(QM)*4+mm][(QN)*2+nn] = __builtin_amdgcn_mfma_f32_16x16x32_bf16(aq[mm][1], bq[nn][1], acc[(QM)*4+mm][(QN)*2+nn], 0, 0, 0); } } } while (0)

#define PH_MID(MMSTMT) \
        __builtin_amdgcn_s_barrier(); \
        asm volatile("s_waitcnt lgkmcnt(0)" ::: "memory"); \
        __builtin_amdgcn_sched_barrier(0); \
        __builtin_amdgcn_s_setprio(1); \
        MMSTMT; \
        __builtin_amdgcn_s_setprio(0); \
        __builtin_amdgcn_sched_barrier(0);

    const int nt = K >> 6;          // K-tiles (even: 12 or 48)
    const int nIter = nt >> 1;
    // prologue: stage s0..s6 = tile0{A0,A1,B0,B1}, tile1{A0,A1,B0}
    STG_A(0, 0); STG_A(0, 1); pa += 64;
    STG_B(0, 0); STG_B(0, 1); pb += 64;
    STG_A(1, 0); STG_A(1, 1); pa += 64;
    STG_B(1, 0);
    asm volatile("s_waitcnt vmcnt(6)" ::: "memory");   // tile0 (8 oldest instrs) resident
    __builtin_amdgcn_sched_barrier(0);
    __builtin_amdgcn_s_barrier();

    for (int i = 0; i < nIter; ++i) {
        const bool last = (i == nIter - 1);
        // ======== tile e = 2i (dbuf 0) ========
        // ph1 (qm0,qn0): read A0q+B0q; stage B1(tile o, dbuf1)
        RD_A(0, 0); RD_B(0, 0);
        __builtin_amdgcn_sched_barrier(0);
        STG_B(1, 1); pb += 64;
        PH_MID(MM16(0, 0));
        __builtin_amdgcn_s_barrier();
        // ph2 (qm0,qn1): read B1q; stage A0(e+2, dbuf0)
        RD_B(1, 0);
        __builtin_amdgcn_sched_barrier(0);
        if (!last) STG_A(0, 0);
        PH_MID(MM16(0, 1));
        __builtin_amdgcn_s_barrier();
        // ph3 (qm1,qn1): read A1q; stage A1(e+2)
        RD_A(1, 0);
        __builtin_amdgcn_sched_barrier(0);
        if (!last) { STG_A(0, 1); pa += 64; }
        PH_MID(MM16(1, 1));
        __builtin_amdgcn_s_barrier();
        // ph4 (qm1,qn0): re-read B0q; stage B0(e+2); vmcnt gate for tile o
        RD_B(0, 0);
        __builtin_amdgcn_sched_barrier(0);
        if (!last) STG_B(0, 0);
        PH_MID(MM16(1, 0));
        if (last) asm volatile("s_waitcnt vmcnt(0)" ::: "memory");
        else      asm volatile("s_waitcnt vmcnt(6)" ::: "memory");
        __builtin_amdgcn_sched_barrier(0);
        __builtin_amdgcn_s_barrier();
        // ======== tile o = 2i+1 (dbuf 1) ========
        // ph5 (qm0,qn0); stage B1(e+2, dbuf0)
        RD_A(0, 16384); RD_B(0, 16384);
        __builtin_amdgcn_sched_barrier(0);
        if (!last) { STG_B(0, 1); pb += 64; }
        PH_MID(MM16(0, 0));
        __builtin_amdgcn_s_barrier();
        // ph6 (qm0,qn1); stage A0(o+2, dbuf1)
        RD_B(1, 16384);
        __builtin_amdgcn_sched_barrier(0);
        if (!last) STG_A(1, 0);
        PH_MID(MM16(0, 1));
        __builtin_amdgcn_s_barrier();
        // ph7 (qm1,qn1); stage A1(o+2)
        RD_A(1, 16384);
        __builtin_amdgcn_sched_barrier(0);
        if (!last) { STG_A(1, 1); pa += 64; }
        PH_MID(MM16(1, 1));
        __builtin_amdgcn_s_barrier();
        // ph8 (qm1,qn0); stage B0(o+2); vmcnt gate for next iter
        RD_B(0, 16384);
        __builtin_amdgcn_sched_barrier(0);
        if (!last) STG_B(1, 0);
        PH_MID(MM16(1, 0));
        if (!last) {
            asm volatile("s_waitcnt vmcnt(6)" ::: "memory");
            __builtin_amdgcn_sched_barrier(0);
            __builtin_amdgcn_s_barrier();
        }
    }
#undef STG_A
#undef STG_B
#undef RD_A
#undef RD_B
#undef MM16
#undef PH_MID
}

// bijective XCD-chunked remap (m204) + GROUP_M=4 super-tiling
__device__ __forceinline__ void xcd_remap2(int& bx, int& by) {
    const int gx = gridDim.x;
    const int nwg = gx * gridDim.y;
    const int lin = blockIdx.y * gx + blockIdx.x;
    const int q = nwg >> 3, r = nwg & 7;
    const int xcd = lin & 7, pos = lin >> 3;
    const int nid = (xcd < r ? xcd * (q + 1) : r * (q + 1) + (xcd - r) * q) + pos;
    const int g4 = gx << 2;
    const int grp = nid / g4, rem = nid - grp * g4;
    by = (grp << 2) + (rem & 3);
    bx = rem >> 2;
}

__device__ __forceinline__ void epilogue256(f32x4 acc[8][4], u16* O, const u16* Emul,
                                            int m0, int n0, int N, int mode, bool emul) {
    const int lane = threadIdx.x & 63, wid = threadIdx.x >> 6;
    const int wr = wid >> 2, wc = wid & 3;
    const int r16 = lane & 15, g = lane >> 4;
#pragma unroll
    for (int m = 0; m < 8; ++m)
#pragma unroll
        for (int n = 0; n < 4; ++n)
#pragma unroll
            for (int j = 0; j < 4; ++j) {
                int row = m0 + wr * 128 + m * 16 + g * 4 + j;
                int col = n0 + wc * 64 + n * 16 + r16;
                float v = acc[m][n][j];
                if (mode == 1) v = 1.f / (1.f + expf(-v));
                else if (mode == 2) { v = fmaxf(v, 0.f); v = v * v; }
                size_t o = (size_t)row * N + col;
                if (emul) v *= b2f(Emul[o]);
                O[o] = f2b(v);
            }
}

// ------------------------------------------------ single GEMM (bf16 out), 256x256 tile
template<int MODE, bool EMUL>
__global__ __launch_bounds__(512, 1)
void gemm256(const u16* __restrict__ A, const u16* __restrict__ WT,
             u16* __restrict__ Cout, const u16* __restrict__ Emul, int N, int K) {
    __shared__ u16 L[65536];
    int bx, by;
    xcd_remap2(bx, by);
    const int m0 = by << 8, n0 = bx << 8;
    f32x4 acc[8][4];
#pragma unroll
    for (int i = 0; i < 8; ++i)
#pragma unroll
        for (int j = 0; j < 4; ++j)
#pragma unroll
            for (int q = 0; q < 4; ++q) acc[i][j][q] = 0.f;
    gemm_core256(A, WT, K, m0, n0, L, acc);
    epilogue256(acc, Cout, Emul, m0, n0, N, MODE, EMUL);
}

// ------------------------------------------------ fused K/V/R projections (blockIdx.z = slice)
struct P3 {
    const u16 *A0, *A1, *A2;
    const u16 *W0, *W1, *W2;
    u16 *O0, *O1, *O2;
};
__global__ __launch_bounds__(512, 1)
void proj3(P3 p, int N, int K) {
    __shared__ u16 L[65536];
    const int z = blockIdx.z;
    const u16* A = (z == 0) ? p.A0 : (z == 1) ? p.A1 : p.A2;
    const u16* W = (z == 0) ? p.W0 : (z == 1) ? p.W1 : p.W2;
    u16* O = (z == 0) ? p.O0 : (z == 1) ? p.O1 : p.O2;
    int bx, by;
    xcd_remap2(bx, by);
    const int m0 = by << 8, n0 = bx << 8;
    f32x4 acc[8][4];
#pragma unroll
    for (int i = 0; i < 8; ++i)
#pragma unroll
        for (int j = 0; j < 4; ++j)
#pragma unroll
            for (int q = 0; q < 4; ++q) acc[i][j][q] = 0.f;
    gemm_core256(A, W, K, m0, n0, L, acc);
    epilogue256(acc, O, nullptr, m0, n0, N, (z == 2) ? 1 : 0, false);
}

// ------------------------------------------------ fused FFN1 (relu^2) + Rr (sigmoid)
struct J2 {
    const u16 *A0, *W0; u16 *O0;   // FFN1: N=3072
    const u16 *A1, *W1; u16 *O1;   // Rr:   N=768
};
__global__ __launch_bounds__(512, 1)
void ffn1rr(J2 p, int K) {
    __shared__ u16 L[65536];
    int bx, by;
    xcd_remap2(bx, by);
    const bool isF = (bx < 12);
    const u16* A = isF ? p.A0 : p.A1;
    const u16* W = isF ? p.W0 : p.W1;
    u16* O = isF ? p.O0 : p.O1;
    const int N = isF ? 3072 : 768;
    const int m0 = by << 8;
    const int n0 = (isF ? bx : bx - 12) << 8;
    f32x4 acc[8][4];
#pragma unroll
    for (int i = 0; i < 8; ++i)
#pragma unroll
        for (int j = 0; j < 4; ++j)
#pragma unroll
            for (int q = 0; q < 4; ++q) acc[i][j][q] = 0.f;
    gemm_core256(A, W, K, m0, n0, L, acc);
    epilogue256(acc, O, nullptr, m0, n0, N, isF ? 2 : 1, false);
}

// ------------------------------------------------ WKV segmented scan
__global__ void wkv_p1(const float* __restrict__ td, const u16* __restrict__ K,
                       const u16* __restrict__ V, float* __restrict__ st) {
    int bc = blockIdx.x * 256 + threadIdx.x;
    int seg = blockIdx.y;
    int b = bc / C_, c = bc - b * C_;
    float w = -expf(td[c]);
    size_t off = (size_t)b * T_ * C_ + (size_t)seg * WSEG * C_ + c;
    float aa = 0.f, bb = 0.f, pp = -1e38f;
#pragma unroll 4
    for (int i = 0; i < WSEG; ++i) {
        float kt = b2f(K[off + (size_t)i * C_]);
        float vt = b2f(V[off + (size_t)i * C_]);
        float ww2 = pp + w;
        float p2 = fmaxf(ww2, kt);
        float e1 = expf(ww2 - p2);
        float e2 = expf(kt - p2);
        aa = e1 * aa + e2 * vt;
        bb = e1 * bb + e2;
        pp = p2;
    }
    int sidx = seg * 3 * BC_ + bc;
    st[sidx] = aa; st[sidx + BC_] = bb; st[sidx + 2 * BC_] = pp;
}

// p3 composes its own segment-prefix from st and applies sigmoid(R) gate
__global__ void wkv_p3(const float* __restrict__ td, const float* __restrict__ tf,
                       const u16* __restrict__ K, const u16* __restrict__ V,
                       const u16* __restrict__ R, const float* __restrict__ st,
                       u16* __restrict__ RY) {
    int bc = blockIdx.x * 256 + threadIdx.x;
    int seg = blockIdx.y;
    int b = bc / C_, c = bc - b * C_;
    float w = -expf(td[c]);
    float u = tf[c];
    float wL = w * (float)WSEG;
    float aa = 0.f, bb = 0.f, pp = -1e38f;
    for (int s = 0; s < seg; ++s) {
        int sidx = s * 3 * BC_ + bc;
        float la = st[sidx], lb = st[sidx + BC_], lp = st[sidx + 2 * BC_];
        float ppw = pp + wL;
        float p = fmaxf(ppw, lp);
        float e1 = expf(ppw - p), e2 = expf(lp - p);
        aa = e1 * aa + e2 * la;
        bb = e1 * bb + e2 * lb;
        pp = p;
    }
    size_t off = (size_t)b * T_ * C_ + (size_t)seg * WSEG * C_ + c;
#pragma unroll 4
    for (int i = 0; i < WSEG; ++i) {
        float kt = b2f(K[off + (size_t)i * C_]);
        float vt = b2f(V[off + (size_t)i * C_]);
        float rr = b2f(R[off + (size_t)i * C_]);
        float ww = u + kt;
        float p = fmaxf(pp, ww);
        float e1 = expf(pp - p);
        float e2 = expf(ww - p);
        RY[off + (size_t)i * C_] = f2b(rr * (e1 * aa + e2 * vt) / (e1 * bb + e2));
        float ww2 = pp + w;
        float p2 = fmaxf(ww2, kt);
        float e1b = expf(ww2 - p2);
        float e2b = expf(kt - p2);
        aa = e1b * aa + e2b * vt;
        bb = e1b * bb + e2b;
        pp = p2;
    }
}

// ------------------------------------------------ LIF + residual (bf16 input, segmented warm-up)
__global__ void lif_add_b(const u16* __restrict__ cur, const float* __restrict__ base,
                          float* __restrict__ out) {
    int bc = blockIdx.x * 256 + threadIdx.x;
    int seg = blockIdx.y;
    int b = bc / C_, c = bc - b * C_;
    size_t rowbase = (size_t)b * T_ * C_ + c;
    int t0 = seg * LSEG;
    int tw = t0 - LWARM; if (tw < 0) tw = 0;
    int nw = t0 - tw;
    float v = 0.f;
    const u16* cp = cur + rowbase + (size_t)tw * C_;
#pragma unroll 8
    for (int i = 0; i < nw; ++i) {
        float xt = b2f(cp[(size_t)i * C_]);
        v += (xt - v) * 0.5f;
        v = (v >= 1.f) ? 0.f : v;
    }
    const u16* c2 = cur + rowbase + (size_t)t0 * C_;
    const float* bp = base + rowbase + (size_t)t0 * C_;
    float* op = out + rowbase + (size_t)t0 * C_;
#pragma unroll 8
    for (int i = 0; i < LSEG; ++i) {
        float xt = b2f(c2[(size_t)i * C_]);
        v += (xt - v) * 0.5f;
        float sp = (v >= 1.f) ? 1.f : 0.f;
        op[(size_t)i * C_] = bp[(size_t)i * C_] + sp;
        v = (sp > 0.f) ? 0.f : v;
    }
}

// ------------------------------------------------ launcher
extern "C" void kernel_launch(void* const* d_in, const int* in_sizes, int n_in,
                              void* d_out, int out_size, void* d_ws, size_t ws_size,
                              hipStream_t stream) {
    const float* x    = (const float*)d_in[0];
    const float* ln1w = (const float*)d_in[1];
    const float* ln1b = (const float*)d_in[2];
    const float* ln2w = (const float*)d_in[3];
    const float* ln2b = (const float*)d_in[4];
    const float* td   = (const float*)d_in[5];
    const float* tf   = (const float*)d_in[6];
    const float* amk  = (const float*)d_in[7];
    const float* amv  = (const float*)d_in[8];
    const float* amr  = (const float*)d_in[9];
    const float* aWk  = (const float*)d_in[10];
    const float* aWv  = (const float*)d_in[11];
    const float* aWr  = (const float*)d_in[12];
    const float* aWo  = (const float*)d_in[13];
    const float* fmk  = (const float*)d_in[14];
    const float* fmr  = (const float*)d_in[15];
    const float* fWk  = (const float*)d_in[16];
    const float* fWv  = (const float*)d_in[17];
    const float* fWr  = (const float*)d_in[18];
    float* out = (float*)d_out;

    const size_t NBC = (size_t)BT_ * C_;
    u16* WkT = (u16*)d_ws;
    u16* WvT = WkT + 589824;
    u16* WrT = WvT + 589824;
    u16* WoT = WrT + 589824;
    u16* FrT = WoT + 589824;
    u16* FkT = FrT + 589824;                  // [3072][768]
    u16* FvT = FkT + 2359296;                 // [768][3072]
    float* st  = (float*)(FvT + 2359296);
    u16* S0 = (u16*)(st + NWSEG * 3 * BC_);
    u16* S1 = S0 + NBC;
    u16* S2 = S1 + NBC;
    u16* S3 = S2 + NBC;
    u16* Hbuf = S3 + NBC;
    size_t fixed_b = (size_t)((char*)Hbuf - (char*)d_ws);

    int NCH = 4;
    if (ws_size >= fixed_b + ((size_t)BT_ * H_ + NBC) * 2) NCH = 1;
    else if (ws_size >= fixed_b + ((size_t)(BT_ / 2) * H_ + NBC / 2) * 2) NCH = 2;
    const int CH = BT_ / NCH;
    u16* Fbuf = Hbuf + (size_t)CH * H_;

    u16* Kb = (u16*)d_out;
    u16* Vb = Kb + NBC;

    // 0. weights -> bf16 [N][K]
    {
        TC7 jobs;
        const float* srcs[7] = {aWk, aWv, aWr, aWo, fWr, fWk, fWv};
        u16* dsts[7] = {WkT, WvT, WrT, WoT, FrT, FkT, FvT};
        int Rs[7]    = {768, 768, 768, 768, 768, 768, 3072};
        int Ns[7]    = {768, 768, 768, 768, 768, 3072, 768};
        int b0 = 0;
        for (int k = 0; k < 7; ++k) {
            jobs.j[k].s = srcs[k]; jobs.j[k].d = dsts[k];
            jobs.j[k].R = Rs[k]; jobs.j[k].Ncol = Ns[k];
            jobs.j[k].nbx = Ns[k] / 32; jobs.j[k].b0 = b0;
            b0 += (Ns[k] / 32) * (Rs[k] / 32);
        }
        tcast_all<<<b0, 256, 0, stream>>>(jobs);
    }

    // 1. xk,xv,xr = mix(ln1(x)) -> S0,S1,S2
    lnmix<3><<<BT_, 256, 0, stream>>>(x, ln1w, ln1b, amk, amv, amr, S0, S1, S2);
    // 2. K,V,sigmoid(R)
    {
        P3 p{S0, S1, S2, WkT, WvT, WrT, Kb, Vb, S3};
        proj3<<<dim3(3, 64, 3), 512, 0, stream>>>(p, C_, C_);
    }
    // 3. RY = sigmoid(R) * wkv(K,V) -> S0
    wkv_p1<<<dim3(BC_ / 256, NWSEG), 256, 0, stream>>>(td, Kb, Vb, st);
    wkv_p3<<<dim3(BC_ / 256, NWSEG), 256, 0, stream>>>(td, tf, Kb, Vb, S3, st, S0);
    // 4. A_out = RY @ Wo -> bf16 S1
    gemm256<0, false><<<dim3(3, 64), 512, 0, stream>>>(S0, WoT, S1, nullptr, C_, C_);
    // 5. X2 = x + lif(A_out) -> d_out
    lif_add_b<<<dim3(BC_ / 256, NLSEG), 256, 0, stream>>>(S1, x, out);
    // 6. xk2 -> S0, xr2 -> S1
    lnmix<2><<<BT_, 256, 0, stream>>>(out, ln2w, ln2b, fmk, fmr, nullptr, S0, S1, nullptr);

    if (NCH == 1) {
        J2 p{S0, FkT, Hbuf, S1, FrT, S2};
        ffn1rr<<<dim3(15, 64), 512, 0, stream>>>(p, C_);
        gemm256<0, true><<<dim3(3, 64), 512, 0, stream>>>(Hbuf, FvT, Fbuf, S2, C_, H_);
        lif_add_b<<<dim3(BC_ / 256, NLSEG), 256, 0, stream>>>(Fbuf, out, out);
    } else {
        gemm256<1, false><<<dim3(3, 64), 512, 0, stream>>>(S1, FrT, S2, nullptr, C_, C_);
        for (int ch = 0; ch < NCH; ++ch) {
            const u16* xk2c = S0 + (size_t)ch * CH * C_;
            const u16* rrc  = S2 + (size_t)ch * CH * C_;
            gemm256<2, false><<<dim3(12, CH / 256), 512, 0, stream>>>(xk2c, FkT, Hbuf, nullptr, H_, C_);
            gemm256<0, true><<<dim3(3, CH / 256), 512, 0, stream>>>(Hbuf, FvT, Fbuf, rrc, C_, H_);
            lif_add_b<<<dim3((CH / T_) * C_ / 256, NLSEG), 256, 0, stream>>>(
                Fbuf, out + (size_t)ch * CH * C_, out + (size_t)ch * CH * C_);
        }
    }
}

// Round 15
// 529.916 us; speedup vs baseline: 1.0698x; 1.0698x over previous
//
#include <hip/hip_runtime.h>

#define B_ 8
#define T_ 2048
#define C_ 768
#define H_ 3072
#define BT_ (B_ * T_)
#define BC_ (B_ * C_)
#define WSEG 64
#define NWSEG 32
#define LSEG 64
#define NLSEG 32
#define LWARM 96

typedef unsigned short u16;
typedef short bf16x8 __attribute__((ext_vector_type(8)));
typedef float f32x4 __attribute__((ext_vector_type(4)));

__device__ __forceinline__ float b2f(u16 u) {
    union { unsigned i; float f; } w; w.i = ((unsigned)u) << 16; return w.f;
}
__device__ __forceinline__ u16 f2b(float f) {
    union { float f; unsigned i; } w; w.f = f;
    return (u16)((w.i + 0x7fffu + ((w.i >> 16) & 1u)) >> 16);
}

typedef __attribute__((address_space(3))) unsigned int lds_u32;
typedef const __attribute__((address_space(1))) unsigned int glb_u32;
__device__ __forceinline__ void gld_lds16(const void* g, void* l) {
    __builtin_amdgcn_global_load_lds((glb_u32*)g, (lds_u32*)l, 16, 0, 0);
}

// ------------------------------------------------ LayerNorm + token-shift mix, wave-per-row
// 512 threads = 8 waves; wave w handles row blockIdx.x*8 + w. No cross-wave sync.
template<int NOUT>
__global__ __launch_bounds__(512)
void lnmixw(const float* __restrict__ x, const float* __restrict__ w,
            const float* __restrict__ b,
            const float* __restrict__ m1, const float* __restrict__ m2,
            const float* __restrict__ m3,
            u16* __restrict__ o1, u16* __restrict__ o2, u16* __restrict__ o3) {
    const int wv = threadIdx.x >> 6, lane = threadIdx.x & 63;
    const int row = blockIdx.x * 8 + wv;
    const int t = row % T_;
    const float4* xr4 = (const float4*)(x + (size_t)row * C_);
    const float4* xp4 = (const float4*)(x + (size_t)(row - 1) * C_);
    float4 c[3], p[3];
#pragma unroll
    for (int j = 0; j < 3; ++j) c[j] = xr4[lane + j * 64];
    if (t > 0) {
#pragma unroll
        for (int j = 0; j < 3; ++j) p[j] = xp4[lane + j * 64];
    } else {
#pragma unroll
        for (int j = 0; j < 3; ++j) p[j] = make_float4(0.f, 0.f, 0.f, 0.f);
    }
    float s = 0.f, s2 = 0.f, ps = 0.f, ps2 = 0.f;
#pragma unroll
    for (int j = 0; j < 3; ++j) {
        s += c[j].x + c[j].y + c[j].z + c[j].w;
        s2 += c[j].x * c[j].x + c[j].y * c[j].y + c[j].z * c[j].z + c[j].w * c[j].w;
        ps += p[j].x + p[j].y + p[j].z + p[j].w;
        ps2 += p[j].x * p[j].x + p[j].y * p[j].y + p[j].z * p[j].z + p[j].w * p[j].w;
    }
#pragma unroll
    for (int off = 32; off > 0; off >>= 1) {
        s += __shfl_down(s, off);  s2 += __shfl_down(s2, off);
        ps += __shfl_down(ps, off); ps2 += __shfl_down(ps2, off);
    }
    s = __shfl(s, 0); s2 = __shfl(s2, 0); ps = __shfl(ps, 0); ps2 = __shfl(ps2, 0);
    const float mu = s * (1.f / C_);
    const float rs = rsqrtf(s2 * (1.f / C_) - mu * mu + 1e-5f);
    const float pmu = ps * (1.f / C_);
    const float prs = rsqrtf(ps2 * (1.f / C_) - pmu * pmu + 1e-5f);
    const size_t ob = (size_t)row * C_;
#pragma unroll
    for (int j = 0; j < 3; ++j) {
        int fi = lane + j * 64;          // float4 index; elements fi*4..fi*4+3
        float4 w4 = ((const float4*)w)[fi];
        float4 b4 = ((const float4*)b)[fi];
        float4 n, np;
        n.x = (c[j].x - mu) * rs * w4.x + b4.x;
        n.y = (c[j].y - mu) * rs * w4.y + b4.y;
        n.z = (c[j].z - mu) * rs * w4.z + b4.z;
        n.w = (c[j].w - mu) * rs * w4.w + b4.w;
        if (t > 0) {
            np.x = (p[j].x - pmu) * prs * w4.x + b4.x;
            np.y = (p[j].y - pmu) * prs * w4.y + b4.y;
            np.z = (p[j].z - pmu) * prs * w4.z + b4.z;
            np.w = (p[j].w - pmu) * prs * w4.w + b4.w;
        } else {
            np = make_float4(0.f, 0.f, 0.f, 0.f);
        }
        float4 mm = ((const float4*)m1)[fi];
        ushort4 ov;
        ov.x = f2b(fmaf(mm.x, n.x - np.x, np.x));
        ov.y = f2b(fmaf(mm.y, n.y - np.y, np.y));
        ov.z = f2b(fmaf(mm.z, n.z - np.z, np.z));
        ov.w = f2b(fmaf(mm.w, n.w - np.w, np.w));
        *(ushort4*)(o1 + ob + fi * 4) = ov;
        mm = ((const float4*)m2)[fi];
        ov.x = f2b(fmaf(mm.x, n.x - np.x, np.x));
        ov.y = f2b(fmaf(mm.y, n.y - np.y, np.y));
        ov.z = f2b(fmaf(mm.z, n.z - np.z, np.z));
        ov.w = f2b(fmaf(mm.w, n.w - np.w, np.w));
        *(ushort4*)(o2 + ob + fi * 4) = ov;
        if constexpr (NOUT == 3) {
            mm = ((const float4*)m3)[fi];
            ov.x = f2b(fmaf(mm.x, n.x - np.x, np.x));
            ov.y = f2b(fmaf(mm.y, n.y - np.y, np.y));
            ov.z = f2b(fmaf(mm.z, n.z - np.z, np.z));
            ov.w = f2b(fmaf(mm.w, n.w - np.w, np.w));
            *(ushort4*)(o3 + ob + fi * 4) = ov;
        }
    }
}

// ------------------------------------------------ batched transpose-cast f32[R][N] -> bf16[N][R]
struct TCJ { const float* s; u16* d; int R, Ncol, nbx, b0; };
struct TC7 { TCJ j[7]; };
__global__ void tcast_all(TC7 jobs) {
    __shared__ float t[32][33];
    int bid = blockIdx.x;
    int ji = 0;
#pragma unroll
    for (int k = 1; k < 7; ++k) if (bid >= jobs.j[k].b0) ji = k;
    TCJ jb = jobs.j[ji];
    int local = bid - jb.b0;
    int bx = local % jb.nbx, by = local / jb.nbx;
    int c0 = bx * 32, r0 = by * 32;
    int col = threadIdx.x & 31, rw = threadIdx.x >> 5;
#pragma unroll
    for (int i = 0; i < 4; ++i) {
        int r = rw + i * 8;
        t[r][col] = jb.s[(size_t)(r0 + r) * jb.Ncol + c0 + col];
    }
    __syncthreads();
#pragma unroll
    for (int i = 0; i < 4; ++i) {
        int r = rw + i * 8;
        jb.d[(size_t)(c0 + r) * jb.R + r0 + col] = f2b(t[col][r]);
    }
}

// ------------------------------------------------ 256x256 GEMM core (round-13 best): 8 waves,
// BK=64, double-buffered LDS, one barrier per K-tile, 64 MFMA per barrier.
__device__ __forceinline__ void gemm_core256(const u16* __restrict__ A,
                                             const u16* __restrict__ WT,
                                             int K, int m0, int n0,
                                             u16* L, f32x4 acc[8][4]) {
    const int tid = threadIdx.x;
    const int lane = tid & 63, wid = tid >> 6;
    const int wr = wid >> 2, wc = wid & 3;
    const int r16 = lane & 15, g = lane >> 4;

    const int srow = tid >> 3;
    const int sunit = tid & 7;
    const int ssw = sunit ^ (srow & 7);
    const u16* gA = A + (size_t)(m0 + srow) * K + ssw * 8;
    const u16* gB = WT + (size_t)(n0 + srow) * K + ssw * 8;
    u16* lA = L + tid * 8;
    u16* lB = L + 16384 + tid * 8;

#define STGA(buf) do { \
        gld_lds16(gA,                   lA + (buf) * 32768); \
        gld_lds16(gA + (size_t)64 * K,  lA + (buf) * 32768 + 4096); \
        gld_lds16(gA + (size_t)128 * K, lA + (buf) * 32768 + 8192); \
        gld_lds16(gA + (size_t)192 * K, lA + (buf) * 32768 + 12288); \
        gA += 64; } while (0)
#define STGB(buf) do { \
        gld_lds16(gB,                   lB + (buf) * 32768); \
        gld_lds16(gB + (size_t)64 * K,  lB + (buf) * 32768 + 4096); \
        gld_lds16(gB + (size_t)128 * K, lB + (buf) * 32768 + 8192); \
        gld_lds16(gB + (size_t)192 * K, lB + (buf) * 32768 + 12288); \
        gB += 64; } while (0)

    int offA[8], offB[4];
#pragma unroll
    for (int m = 0; m < 8; ++m) {
        int row = wr * 128 + m * 16 + r16;
        offA[m] = row * 64 + (g ^ (row & 7)) * 8;
    }
#pragma unroll
    for (int n = 0; n < 4; ++n) {
        int rob = wc * 64 + n * 16 + r16;
        offB[n] = 16384 + rob * 64 + (g ^ (rob & 7)) * 8;
    }

    const int nt = K >> 6;
    STGA(0); STGB(0);
    asm volatile("s_waitcnt vmcnt(0)" ::: "memory");
    __builtin_amdgcn_sched_barrier(0);
    __builtin_amdgcn_s_barrier();

    for (int t = 0; t < nt; ++t) {
        const u16* Lb = L + (t & 1) * 32768;
        const bool stg = (t + 1 < nt);
        bf16x8 a0[8], b0[4];
#pragma unroll
        for (int m = 0; m < 8; ++m) a0[m] = *(const bf16x8*)(Lb + offA[m]);
#pragma unroll
        for (int n = 0; n < 4; ++n) b0[n] = *(const bf16x8*)(Lb + offB[n]);
        __builtin_amdgcn_sched_barrier(0);
        if (stg) { STGA((t + 1) & 1); STGB((t + 1) & 1); }
        asm volatile("s_waitcnt lgkmcnt(0)" ::: "memory");
        __builtin_amdgcn_sched_barrier(0);
        __builtin_amdgcn_s_setprio(1);
#pragma unroll
        for (int m = 0; m < 8; ++m)
#pragma unroll
            for (int n = 0; n < 4; ++n)
                acc[m][n] = __builtin_amdgcn_mfma_f32_16x16x32_bf16(a0[m], b0[n], acc[m][n], 0, 0, 0);
        __builtin_amdgcn_s_setprio(0);
        __builtin_amdgcn_sched_barrier(0);
        bf16x8 a1[8], b1[4];
#pragma unroll
        for (int m = 0; m < 8; ++m) a1[m] = *(const bf16x8*)(Lb + (offA[m] ^ 32));
#pragma unroll
        for (int n = 0; n < 4; ++n) b1[n] = *(const bf16x8*)(Lb + (offB[n] ^ 32));
        asm volatile("s_waitcnt lgkmcnt(0)" ::: "memory");
        __builtin_amdgcn_sched_barrier(0);
        __builtin_amdgcn_s_setprio(1);
#pragma unroll
        for (int m = 0; m < 8; ++m)
#pragma unroll
            for (int n = 0; n < 4; ++n)
                acc[m][n] = __builtin_amdgcn_mfma_f32_16x16x32_bf16(a1[m], b1[n], acc[m][n], 0, 0, 0);
        __builtin_amdgcn_s_setprio(0);
        __builtin_amdgcn_sched_barrier(0);
        if (stg) {
            asm volatile("s_waitcnt vmcnt(0)" ::: "memory");
            __builtin_amdgcn_sched_barrier(0);
            __builtin_amdgcn_s_barrier();
        }
    }
#undef STGA
#undef STGB
}

// bijective XCD-chunked remap (m204) + GROUP_M=4 super-tiling
__device__ __forceinline__ void xcd_remap2(int& bx, int& by) {
    const int gx = gridDim.x;
    const int nwg = gx * gridDim.y;
    const int lin = blockIdx.y * gx + blockIdx.x;
    const int q = nwg >> 3, r = nwg & 7;
    const int xcd = lin & 7, pos = lin >> 3;
    const int nid = (xcd < r ? xcd * (q + 1) : r * (q + 1) + (xcd - r) * q) + pos;
    const int g4 = gx << 2;
    const int grp = nid / g4, rem = nid - grp * g4;
    by = (grp << 2) + (rem & 3);
    bx = rem >> 2;
}

__device__ __forceinline__ void epilogue256(f32x4 acc[8][4], u16* O, const u16* Emul,
                                            int m0, int n0, int N, int mode, bool emul) {
    const int lane = threadIdx.x & 63, wid = threadIdx.x >> 6;
    const int wr = wid >> 2, wc = wid & 3;
    const int r16 = lane & 15, g = lane >> 4;
#pragma unroll
    for (int m = 0; m < 8; ++m)
#pragma unroll
        for (int n = 0; n < 4; ++n)
#pragma unroll
            for (int j = 0; j < 4; ++j) {
                int row = m0 + wr * 128 + m * 16 + g * 4 + j;
                int col = n0 + wc * 64 + n * 16 + r16;
                float v = acc[m][n][j];
                if (mode == 1) v = 1.f / (1.f + expf(-v));
                else if (mode == 2) { v = fmaxf(v, 0.f); v = v * v; }
                size_t o = (size_t)row * N + col;
                if (emul) v *= b2f(Emul[o]);
                O[o] = f2b(v);
            }
}

// ------------------------------------------------ single GEMM (bf16 out), 256x256 tile
template<int MODE, bool EMUL>
__global__ __launch_bounds__(512, 1)
void gemm256(const u16* __restrict__ A, const u16* __restrict__ WT,
             u16* __restrict__ Cout, const u16* __restrict__ Emul, int N, int K) {
    __shared__ u16 L[65536];
    int bx, by;
    xcd_remap2(bx, by);
    const int m0 = by << 8, n0 = bx << 8;
    f32x4 acc[8][4];
#pragma unroll
    for (int i = 0; i < 8; ++i)
#pragma unroll
        for (int j = 0; j < 4; ++j)
#pragma unroll
            for (int q = 0; q < 4; ++q) acc[i][j][q] = 0.f;
    gemm_core256(A, WT, K, m0, n0, L, acc);
    epilogue256(acc, Cout, Emul, m0, n0, N, MODE, EMUL);
}

// ------------------------------------------------ fused K/V/R projections (blockIdx.z = slice)
struct P3 {
    const u16 *A0, *A1, *A2;
    const u16 *W0, *W1, *W2;
    u16 *O0, *O1, *O2;
};
__global__ __launch_bounds__(512, 1)
void proj3(P3 p, int N, int K) {
    __shared__ u16 L[65536];
    const int z = blockIdx.z;
    const u16* A = (z == 0) ? p.A0 : (z == 1) ? p.A1 : p.A2;
    const u16* W = (z == 0) ? p.W0 : (z == 1) ? p.W1 : p.W2;
    u16* O = (z == 0) ? p.O0 : (z == 1) ? p.O1 : p.O2;
    int bx, by;
    xcd_remap2(bx, by);
    const int m0 = by << 8, n0 = bx << 8;
    f32x4 acc[8][4];
#pragma unroll
    for (int i = 0; i < 8; ++i)
#pragma unroll
        for (int j = 0; j < 4; ++j)
#pragma unroll
            for (int q = 0; q < 4; ++q) acc[i][j][q] = 0.f;
    gemm_core256(A, W, K, m0, n0, L, acc);
    epilogue256(acc, O, nullptr, m0, n0, N, (z == 2) ? 1 : 0, false);
}

// ------------------------------------------------ fused FFN1 (relu^2) + Rr (sigmoid)
struct J2 {
    const u16 *A0, *W0; u16 *O0;   // FFN1: N=3072
    const u16 *A1, *W1; u16 *O1;   // Rr:   N=768
};
__global__ __launch_bounds__(512, 1)
void ffn1rr(J2 p, int K) {
    __shared__ u16 L[65536];
    int bx, by;
    xcd_remap2(bx, by);
    const bool isF = (bx < 12);
    const u16* A = isF ? p.A0 : p.A1;
    const u16* W = isF ? p.W0 : p.W1;
    u16* O = isF ? p.O0 : p.O1;
    const int N = isF ? 3072 : 768;
    const int m0 = by << 8;
    const int n0 = (isF ? bx : bx - 12) << 8;
    f32x4 acc[8][4];
#pragma unroll
    for (int i = 0; i < 8; ++i)
#pragma unroll
        for (int j = 0; j < 4; ++j)
#pragma unroll
            for (int q = 0; q < 4; ++q) acc[i][j][q] = 0.f;
    gemm_core256(A, W, K, m0, n0, L, acc);
    epilogue256(acc, O, nullptr, m0, n0, N, isF ? 2 : 1, false);
}

// ------------------------------------------------ WKV segmented scan, 2 channels/thread
__global__ void wkv_p1(const float* __restrict__ td, const u16* __restrict__ K,
                       const u16* __restrict__ V, float* __restrict__ st) {
    int idx = blockIdx.x * 256 + threadIdx.x;   // < BC_/2
    int seg = blockIdx.y;
    int c2 = idx * 2;
    int b = c2 / C_, c = c2 - b * C_;
    float w0 = -expf(td[c]), w1 = -expf(td[c + 1]);
    size_t off = (size_t)b * T_ * C_ + (size_t)seg * WSEG * C_ + c;
    float aa0 = 0.f, bb0 = 0.f, pp0 = -1e38f;
    float aa1 = 0.f, bb1 = 0.f, pp1 = -1e38f;
#pragma unroll 4
    for (int i = 0; i < WSEG; ++i) {
        ushort2 k2 = *(const ushort2*)(K + off + (size_t)i * C_);
        ushort2 v2 = *(const ushort2*)(V + off + (size_t)i * C_);
        {
            float kt = b2f(k2.x), vt = b2f(v2.x);
            float ww = pp0 + w0;
            float p = fmaxf(ww, kt);
            float e1 = expf(ww - p), e2 = expf(kt - p);
            aa0 = e1 * aa0 + e2 * vt; bb0 = e1 * bb0 + e2; pp0 = p;
        }
        {
            float kt = b2f(k2.y), vt = b2f(v2.y);
            float ww = pp1 + w1;
            float p = fmaxf(ww, kt);
            float e1 = expf(ww - p), e2 = expf(kt - p);
            aa1 = e1 * aa1 + e2 * vt; bb1 = e1 * bb1 + e2; pp1 = p;
        }
    }
    int sidx = seg * 3 * BC_ + b * C_ + c;
    *(float2*)(st + sidx) = make_float2(aa0, aa1);
    *(float2*)(st + sidx + BC_) = make_float2(bb0, bb1);
    *(float2*)(st + sidx + 2 * BC_) = make_float2(pp0, pp1);
}

// p3 composes its own segment-prefix from st and applies sigmoid(R) gate; 2 channels/thread
__global__ void wkv_p3(const float* __restrict__ td, const float* __restrict__ tf,
                       const u16* __restrict__ K, const u16* __restrict__ V,
                       const u16* __restrict__ R, const float* __restrict__ st,
                       u16* __restrict__ RY) {
    int idx = blockIdx.x * 256 + threadIdx.x;   // < BC_/2
    int seg = blockIdx.y;
    int c2 = idx * 2;
    int b = c2 / C_, c = c2 - b * C_;
    float w0 = -expf(td[c]), w1 = -expf(td[c + 1]);
    float u0 = tf[c], u1 = tf[c + 1];
    float wL0 = w0 * (float)WSEG, wL1 = w1 * (float)WSEG;
    float aa0 = 0.f, bb0 = 0.f, pp0 = -1e38f;
    float aa1 = 0.f, bb1 = 0.f, pp1 = -1e38f;
    for (int s = 0; s < seg; ++s) {
        int sidx = s * 3 * BC_ + b * C_ + c;
        float2 la = *(const float2*)(st + sidx);
        float2 lb = *(const float2*)(st + sidx + BC_);
        float2 lp = *(const float2*)(st + sidx + 2 * BC_);
        {
            float ppw = pp0 + wL0;
            float p = fmaxf(ppw, lp.x);
            float e1 = expf(ppw - p), e2 = expf(lp.x - p);
            aa0 = e1 * aa0 + e2 * la.x; bb0 = e1 * bb0 + e2 * lb.x; pp0 = p;
        }
        {
            float ppw = pp1 + wL1;
            float p = fmaxf(ppw, lp.y);
            float e1 = expf(ppw - p), e2 = expf(lp.y - p);
            aa1 = e1 * aa1 + e2 * la.y; bb1 = e1 * bb1 + e2 * lb.y; pp1 = p;
        }
    }
    size_t off = (size_t)b * T_ * C_ + (size_t)seg * WSEG * C_ + c;
#pragma unroll 4
    for (int i = 0; i < WSEG; ++i) {
        ushort2 k2 = *(const ushort2*)(K + off + (size_t)i * C_);
        ushort2 v2 = *(const ushort2*)(V + off + (size_t)i * C_);
        ushort2 r2 = *(const ushort2*)(R + off + (size_t)i * C_);
        ushort2 o2v;
        {
            float kt = b2f(k2.x), vt = b2f(v2.x), rr = b2f(r2.x);
            float ww = u0 + kt;
            float p = fmaxf(pp0, ww);
            float e1 = expf(pp0 - p), e2 = expf(ww - p);
            o2v.x = f2b(rr * (e1 * aa0 + e2 * vt) / (e1 * bb0 + e2));
            float ww2 = pp0 + w0;
            float p2 = fmaxf(ww2, kt);
            float e1b = expf(ww2 - p2), e2b = expf(kt - p2);
            aa0 = e1b * aa0 + e2b * vt; bb0 = e1b * bb0 + e2b; pp0 = p2;
        }
        {
            float kt = b2f(k2.y), vt = b2f(v2.y), rr = b2f(r2.y);
            float ww = u1 + kt;
            float p = fmaxf(pp1, ww);
            float e1 = expf(pp1 - p), e2 = expf(ww - p);
            o2v.y = f2b(rr * (e1 * aa1 + e2 * vt) / (e1 * bb1 + e2));
            float ww2 = pp1 + w1;
            float p2 = fmaxf(ww2, kt);
            float e1b = expf(ww2 - p2), e2b = expf(kt - p2);
            aa1 = e1b * aa1 + e2b * vt; bb1 = e1b * bb1 + e2b; pp1 = p2;
        }
        *(ushort2*)(RY + off + (size_t)i * C_) = o2v;
    }
}

// ------------------------------------------------ LIF + residual, 2 channels/thread
__global__ void lif_add_b(const u16* __restrict__ cur, const float* __restrict__ base,
                          float* __restrict__ out) {
    int idx = blockIdx.x * 256 + threadIdx.x;   // < rows*C_/2 for this slice
    int seg = blockIdx.y;
    int c2 = idx * 2;
    int b = c2 / C_, c = c2 - b * C_;
    size_t rowbase = (size_t)b * T_ * C_ + c;
    int t0 = seg * LSEG;
    int tw = t0 - LWARM; if (tw < 0) tw = 0;
    int nw = t0 - tw;
    float v0 = 0.f, v1 = 0.f;
    const u16* cp = cur + rowbase + (size_t)tw * C_;
#pragma unroll 8
    for (int i = 0; i < nw; ++i) {
        ushort2 x2 = *(const ushort2*)(cp + (size_t)i * C_);
        v0 += (b2f(x2.x) - v0) * 0.5f;
        v0 = (v0 >= 1.f) ? 0.f : v0;
        v1 += (b2f(x2.y) - v1) * 0.5f;
        v1 = (v1 >= 1.f) ? 0.f : v1;
    }
    const u16* cq = cur + rowbase + (size_t)t0 * C_;
    const float* bp = base + rowbase + (size_t)t0 * C_;
    float* op = out + rowbase + (size_t)t0 * C_;
#pragma unroll 8
    for (int i = 0; i < LSEG; ++i) {
        ushort2 x2 = *(const ushort2*)(cq + (size_t)i * C_);
        float2 b2 = *(const float2*)(bp + (size_t)i * C_);
        v0 += (b2f(x2.x) - v0) * 0.5f;
        float s0 = (v0 >= 1.f) ? 1.f : 0.f;
        v1 += (b2f(x2.y) - v1) * 0.5f;
        float s1 = (v1 >= 1.f) ? 1.f : 0.f;
        *(float2*)(op + (size_t)i * C_) = make_float2(b2.x + s0, b2.y + s1);
        v0 = (s0 > 0.f) ? 0.f : v0;
        v1 = (s1 > 0.f) ? 0.f : v1;
    }
}

// ------------------------------------------------ launcher
extern "C" void kernel_launch(void* const* d_in, const int* in_sizes, int n_in,
                              void* d_out, int out_size, void* d_ws, size_t ws_size,
                              hipStream_t stream) {
    const float* x    = (const float*)d_in[0];
    const float* ln1w = (const float*)d_in[1];
    const float* ln1b = (const float*)d_in[2];
    const float* ln2w = (const float*)d_in[3];
    const float* ln2b = (const float*)d_in[4];
    const float* td   = (const float*)d_in[5];
    const float* tf   = (const float*)d_in[6];
    const float* amk  = (const float*)d_in[7];
    const float* amv  = (const float*)d_in[8];
    const float* amr  = (const float*)d_in[9];
    const float* aWk  = (const float*)d_in[10];
    const float* aWv  = (const float*)d_in[11];
    const float* aWr  = (const float*)d_in[12];
    const float* aWo  = (const float*)d_in[13];
    const float* fmk  = (const float*)d_in[14];
    const float* fmr  = (const float*)d_in[15];
    const float* fWk  = (const float*)d_in[16];
    const float* fWv  = (const float*)d_in[17];
    const float* fWr  = (const float*)d_in[18];
    float* out = (float*)d_out;

    const size_t NBC = (size_t)BT_ * C_;
    u16* WkT = (u16*)d_ws;
    u16* WvT = WkT + 589824;
    u16* WrT = WvT + 589824;
    u16* WoT = WrT + 589824;
    u16* FrT = WoT + 589824;
    u16* FkT = FrT + 589824;                  // [3072][768]
    u16* FvT = FkT + 2359296;                 // [768][3072]
    float* st  = (float*)(FvT + 2359296);
    u16* S0 = (u16*)(st + NWSEG * 3 * BC_);
    u16* S1 = S0 + NBC;
    u16* S2 = S1 + NBC;
    u16* S3 = S2 + NBC;
    u16* Hbuf = S3 + NBC;
    size_t fixed_b = (size_t)((char*)Hbuf - (char*)d_ws);

    int NCH = 4;
    if (ws_size >= fixed_b + ((size_t)BT_ * H_ + NBC) * 2) NCH = 1;
    else if (ws_size >= fixed_b + ((size_t)(BT_ / 2) * H_ + NBC / 2) * 2) NCH = 2;
    const int CH = BT_ / NCH;
    u16* Fbuf = Hbuf + (size_t)CH * H_;

    u16* Kb = (u16*)d_out;
    u16* Vb = Kb + NBC;

    // 0. weights -> bf16 [N][K]
    {
        TC7 jobs;
        const float* srcs[7] = {aWk, aWv, aWr, aWo, fWr, fWk, fWv};
        u16* dsts[7] = {WkT, WvT, WrT, WoT, FrT, FkT, FvT};
        int Rs[7]    = {768, 768, 768, 768, 768, 768, 3072};
        int Ns[7]    = {768, 768, 768, 768, 768, 3072, 768};
        int b0 = 0;
        for (int k = 0; k < 7; ++k) {
            jobs.j[k].s = srcs[k]; jobs.j[k].d = dsts[k];
            jobs.j[k].R = Rs[k]; jobs.j[k].Ncol = Ns[k];
            jobs.j[k].nbx = Ns[k] / 32; jobs.j[k].b0 = b0;
            b0 += (Ns[k] / 32) * (Rs[k] / 32);
        }
        tcast_all<<<b0, 256, 0, stream>>>(jobs);
    }

    // 1. xk,xv,xr = mix(ln1(x)) -> S0,S1,S2
    lnmixw<3><<<BT_ / 8, 512, 0, stream>>>(x, ln1w, ln1b, amk, amv, amr, S0, S1, S2);
    // 2. K,V,sigmoid(R)
    {
        P3 p{S0, S1, S2, WkT, WvT, WrT, Kb, Vb, S3};
        proj3<<<dim3(3, 64, 3), 512, 0, stream>>>(p, C_, C_);
    }
    // 3. RY = sigmoid(R) * wkv(K,V) -> S0
    wkv_p1<<<dim3(BC_ / 512, NWSEG), 256, 0, stream>>>(td, Kb, Vb, st);
    wkv_p3<<<dim3(BC_ / 512, NWSEG), 256, 0, stream>>>(td, tf, Kb, Vb, S3, st, S0);
    // 4. A_out = RY @ Wo -> bf16 S1
    gemm256<0, false><<<dim3(3, 64), 512, 0, stream>>>(S0, WoT, S1, nullptr, C_, C_);
    // 5. X2 = x + lif(A_out) -> d_out
    lif_add_b<<<dim3(BC_ / 512, NLSEG), 256, 0, stream>>>(S1, x, out);
    // 6. xk2 -> S0, xr2 -> S1
    lnmixw<2><<<BT_ / 8, 512, 0, stream>>>(out, ln2w, ln2b, fmk, fmr, nullptr, S0, S1, nullptr);

    if (NCH == 1) {
        J2 p{S0, FkT, Hbuf, S1, FrT, S2};
        ffn1rr<<<dim3(15, 64), 512, 0, stream>>>(p, C_);
        gemm256<0, true><<<dim3(3, 64), 512, 0, stream>>>(Hbuf, FvT, Fbuf, S2, C_, H_);
        lif_add_b<<<dim3(BC_ / 512, NLSEG), 256, 0, stream>>>(Fbuf, out, out);
    } else {
        gemm256<1, false><<<dim3(3, 64), 512, 0, stream>>>(S1, FrT, S2, nullptr, C_, C_);
        for (int ch = 0; ch < NCH; ++ch) {
            const u16* xk2c = S0 + (size_t)ch * CH * C_;
            const u16* rrc  = S2 + (size_t)ch * CH * C_;
            gemm256<2, false><<<dim3(12, CH / 256), 512, 0, stream>>>(xk2c, FkT, Hbuf, nullptr, H_, C_);
            gemm256<0, true><<<dim3(3, CH / 256), 512, 0, stream>>>(Hbuf, FvT, Fbuf, rrc, C_, H_);
            lif_add_b<<<dim3((CH / T_) * C_ / 512, NLSEG), 256, 0, stream>>>(
                Fbuf, out + (size_t)ch * CH * C_, out + (size_t)ch * CH * C_);
        }
    }
}

// Round 16
// 521.446 us; speedup vs baseline: 1.0872x; 1.0162x over previous
//
#include <hip/hip_runtime.h>

#define B_ 8
#define T_ 2048
#define C_ 768
#define H_ 3072
#define BT_ (B_ * T_)
#define BC_ (B_ * C_)
#define WSEG 64
#define NWSEG 32
#define LSEG 64
#define NLSEG 32
#define LWARM 96

typedef unsigned short u16;
typedef short bf16x8 __attribute__((ext_vector_type(8)));
typedef float f32x4 __attribute__((ext_vector_type(4)));

__device__ __forceinline__ float b2f(u16 u) {
    union { unsigned i; float f; } w; w.i = ((unsigned)u) << 16; return w.f;
}
__device__ __forceinline__ u16 f2b(float f) {
    union { float f; unsigned i; } w; w.f = f;
    return (u16)((w.i + 0x7fffu + ((w.i >> 16) & 1u)) >> 16);
}

typedef __attribute__((address_space(3))) unsigned int lds_u32;
typedef const __attribute__((address_space(1))) unsigned int glb_u32;
__device__ __forceinline__ void gld_lds16(const void* g, void* l) {
    __builtin_amdgcn_global_load_lds((glb_u32*)g, (lds_u32*)l, 16, 0, 0);
}

// ------------------------------------------------ LayerNorm + token-shift mix, wave-per-row
template<int NOUT>
__global__ __launch_bounds__(512)
void lnmixw(const float* __restrict__ x, const float* __restrict__ w,
            const float* __restrict__ b,
            const float* __restrict__ m1, const float* __restrict__ m2,
            const float* __restrict__ m3,
            u16* __restrict__ o1, u16* __restrict__ o2, u16* __restrict__ o3) {
    const int wv = threadIdx.x >> 6, lane = threadIdx.x & 63;
    const int row = blockIdx.x * 8 + wv;
    const int t = row % T_;
    const float4* xr4 = (const float4*)(x + (size_t)row * C_);
    const float4* xp4 = (const float4*)(x + (size_t)(row - 1) * C_);
    float4 c[3], p[3];
#pragma unroll
    for (int j = 0; j < 3; ++j) c[j] = xr4[lane + j * 64];
    if (t > 0) {
#pragma unroll
        for (int j = 0; j < 3; ++j) p[j] = xp4[lane + j * 64];
    } else {
#pragma unroll
        for (int j = 0; j < 3; ++j) p[j] = make_float4(0.f, 0.f, 0.f, 0.f);
    }
    float s = 0.f, s2 = 0.f, ps = 0.f, ps2 = 0.f;
#pragma unroll
    for (int j = 0; j < 3; ++j) {
        s += c[j].x + c[j].y + c[j].z + c[j].w;
        s2 += c[j].x * c[j].x + c[j].y * c[j].y + c[j].z * c[j].z + c[j].w * c[j].w;
        ps += p[j].x + p[j].y + p[j].z + p[j].w;
        ps2 += p[j].x * p[j].x + p[j].y * p[j].y + p[j].z * p[j].z + p[j].w * p[j].w;
    }
#pragma unroll
    for (int off = 32; off > 0; off >>= 1) {
        s += __shfl_down(s, off);  s2 += __shfl_down(s2, off);
        ps += __shfl_down(ps, off); ps2 += __shfl_down(ps2, off);
    }
    s = __shfl(s, 0); s2 = __shfl(s2, 0); ps = __shfl(ps, 0); ps2 = __shfl(ps2, 0);
    const float mu = s * (1.f / C_);
    const float rs = rsqrtf(s2 * (1.f / C_) - mu * mu + 1e-5f);
    const float pmu = ps * (1.f / C_);
    const float prs = rsqrtf(ps2 * (1.f / C_) - pmu * pmu + 1e-5f);
    const size_t ob = (size_t)row * C_;
#pragma unroll
    for (int j = 0; j < 3; ++j) {
        int fi = lane + j * 64;
        float4 w4 = ((const float4*)w)[fi];
        float4 b4 = ((const float4*)b)[fi];
        float4 n, np;
        n.x = (c[j].x - mu) * rs * w4.x + b4.x;
        n.y = (c[j].y - mu) * rs * w4.y + b4.y;
        n.z = (c[j].z - mu) * rs * w4.z + b4.z;
        n.w = (c[j].w - mu) * rs * w4.w + b4.w;
        if (t > 0) {
            np.x = (p[j].x - pmu) * prs * w4.x + b4.x;
            np.y = (p[j].y - pmu) * prs * w4.y + b4.y;
            np.z = (p[j].z - pmu) * prs * w4.z + b4.z;
            np.w = (p[j].w - pmu) * prs * w4.w + b4.w;
        } else {
            np = make_float4(0.f, 0.f, 0.f, 0.f);
        }
        float4 mm = ((const float4*)m1)[fi];
        ushort4 ov;
        ov.x = f2b(fmaf(mm.x, n.x - np.x, np.x));
        ov.y = f2b(fmaf(mm.y, n.y - np.y, np.y));
        ov.z = f2b(fmaf(mm.z, n.z - np.z, np.z));
        ov.w = f2b(fmaf(mm.w, n.w - np.w, np.w));
        *(ushort4*)(o1 + ob + fi * 4) = ov;
        mm = ((const float4*)m2)[fi];
        ov.x = f2b(fmaf(mm.x, n.x - np.x, np.x));
        ov.y = f2b(fmaf(mm.y, n.y - np.y, np.y));
        ov.z = f2b(fmaf(mm.z, n.z - np.z, np.z));
        ov.w = f2b(fmaf(mm.w, n.w - np.w, np.w));
        *(ushort4*)(o2 + ob + fi * 4) = ov;
        if constexpr (NOUT == 3) {
            mm = ((const float4*)m3)[fi];
            ov.x = f2b(fmaf(mm.x, n.x - np.x, np.x));
            ov.y = f2b(fmaf(mm.y, n.y - np.y, np.y));
            ov.z = f2b(fmaf(mm.z, n.z - np.z, np.z));
            ov.w = f2b(fmaf(mm.w, n.w - np.w, np.w));
            *(ushort4*)(o3 + ob + fi * 4) = ov;
        }
    }
}

// ------------------------------------------------ batched transpose-cast f32[R][N] -> bf16[N][R]
struct TCJ { const float* s; u16* d; int R, Ncol, nbx, b0; };
struct TC7 { TCJ j[7]; };
__global__ void tcast_all(TC7 jobs) {
    __shared__ float t[32][33];
    int bid = blockIdx.x;
    int ji = 0;
#pragma unroll
    for (int k = 1; k < 7; ++k) if (bid >= jobs.j[k].b0) ji = k;
    TCJ jb = jobs.j[ji];
    int local = bid - jb.b0;
    int bx = local % jb.nbx, by = local / jb.nbx;
    int c0 = bx * 32, r0 = by * 32;
    int col = threadIdx.x & 31, rw = threadIdx.x >> 5;
#pragma unroll
    for (int i = 0; i < 4; ++i) {
        int r = rw + i * 8;
        t[r][col] = jb.s[(size_t)(r0 + r) * jb.Ncol + c0 + col];
    }
    __syncthreads();
#pragma unroll
    for (int i = 0; i < 4; ++i) {
        int r = rw + i * 8;
        jb.d[(size_t)(c0 + r) * jb.R + r0 + col] = f2b(t[col][r]);
    }
}

// ------------------------------------------------ 128x128 GEMM core: 4 waves (2Mx2N, 64x64/wave),
// BK=64, double-buffered LDS = 64KB -> 2 blocks/CU. One barrier per K-tile, 32 MFMA/barrier,
// inter-block overlap hides the barrier drain (m114).
__device__ __forceinline__ void gemm_core128(const u16* __restrict__ A,
                                             const u16* __restrict__ WT,
                                             int K, int m0, int n0,
                                             u16* L, f32x4 acc[4][4]) {
    const int tid = threadIdx.x;
    const int lane = tid & 63, wid = tid >> 6;
    const int wr = wid >> 1, wc = wid & 1;
    const int r16 = lane & 15, g = lane >> 4;

    const int srow = tid >> 3;                 // 0..31
    const int sunit = tid & 7;
    const int ssw = sunit ^ (srow & 7);
    const u16* gA = A + (size_t)(m0 + srow) * K + ssw * 8;
    const u16* gB = WT + (size_t)(n0 + srow) * K + ssw * 8;
    u16* lA = L + tid * 8;
    u16* lB = L + 8192 + tid * 8;

#define STGA(buf) do { \
        gld_lds16(gA,                  lA + (buf) * 16384); \
        gld_lds16(gA + (size_t)32 * K, lA + (buf) * 16384 + 2048); \
        gld_lds16(gA + (size_t)64 * K, lA + (buf) * 16384 + 4096); \
        gld_lds16(gA + (size_t)96 * K, lA + (buf) * 16384 + 6144); \
        gA += 64; } while (0)
#define STGB(buf) do { \
        gld_lds16(gB,                  lB + (buf) * 16384); \
        gld_lds16(gB + (size_t)32 * K, lB + (buf) * 16384 + 2048); \
        gld_lds16(gB + (size_t)64 * K, lB + (buf) * 16384 + 4096); \
        gld_lds16(gB + (size_t)96 * K, lB + (buf) * 16384 + 6144); \
        gB += 64; } while (0)

    int offA[4], offB[4];
#pragma unroll
    for (int m = 0; m < 4; ++m) {
        int row = wr * 64 + m * 16 + r16;
        offA[m] = row * 64 + (g ^ (row & 7)) * 8;
    }
#pragma unroll
    for (int n = 0; n < 4; ++n) {
        int rob = wc * 64 + n * 16 + r16;
        offB[n] = 8192 + rob * 64 + (g ^ (rob & 7)) * 8;
    }

    const int nt = K >> 6;
    STGA(0); STGB(0);
    asm volatile("s_waitcnt vmcnt(0)" ::: "memory");
    __builtin_amdgcn_sched_barrier(0);
    __builtin_amdgcn_s_barrier();

    for (int t = 0; t < nt; ++t) {
        const u16* Lb = L + (t & 1) * 16384;
        const bool stg = (t + 1 < nt);
        bf16x8 a0[4], b0[4];
#pragma unroll
        for (int m = 0; m < 4; ++m) a0[m] = *(const bf16x8*)(Lb + offA[m]);
#pragma unroll
        for (int n = 0; n < 4; ++n) b0[n] = *(const bf16x8*)(Lb + offB[n]);
        __builtin_amdgcn_sched_barrier(0);
        if (stg) { STGA((t + 1) & 1); STGB((t + 1) & 1); }
        asm volatile("s_waitcnt lgkmcnt(0)" ::: "memory");
        __builtin_amdgcn_sched_barrier(0);
        __builtin_amdgcn_s_setprio(1);
#pragma unroll
        for (int m = 0; m < 4; ++m)
#pragma unroll
            for (int n = 0; n < 4; ++n)
                acc[m][n] = __builtin_amdgcn_mfma_f32_16x16x32_bf16(a0[m], b0[n], acc[m][n], 0, 0, 0);
        __builtin_amdgcn_s_setprio(0);
        __builtin_amdgcn_sched_barrier(0);
        bf16x8 a1[4], b1[4];
#pragma unroll
        for (int m = 0; m < 4; ++m) a1[m] = *(const bf16x8*)(Lb + (offA[m] ^ 32));
#pragma unroll
        for (int n = 0; n < 4; ++n) b1[n] = *(const bf16x8*)(Lb + (offB[n] ^ 32));
        asm volatile("s_waitcnt lgkmcnt(0)" ::: "memory");
        __builtin_amdgcn_sched_barrier(0);
        __builtin_amdgcn_s_setprio(1);
#pragma unroll
        for (int m = 0; m < 4; ++m)
#pragma unroll
            for (int n = 0; n < 4; ++n)
                acc[m][n] = __builtin_amdgcn_mfma_f32_16x16x32_bf16(a1[m], b1[n], acc[m][n], 0, 0, 0);
        __builtin_amdgcn_s_setprio(0);
        __builtin_amdgcn_sched_barrier(0);
        if (stg) {
            asm volatile("s_waitcnt vmcnt(0)" ::: "memory");
            __builtin_amdgcn_sched_barrier(0);
            __builtin_amdgcn_s_barrier();
        }
    }
#undef STGA
#undef STGB
}

// bijective XCD-chunked remap (m204) + GROUP_M=4 super-tiling
__device__ __forceinline__ void xcd_remap2(int& bx, int& by) {
    const int gx = gridDim.x;
    const int nwg = gx * gridDim.y;
    const int lin = blockIdx.y * gx + blockIdx.x;
    const int q = nwg >> 3, r = nwg & 7;
    const int xcd = lin & 7, pos = lin >> 3;
    const int nid = (xcd < r ? xcd * (q + 1) : r * (q + 1) + (xcd - r) * q) + pos;
    const int g4 = gx << 2;
    const int grp = nid / g4, rem = nid - grp * g4;
    by = (grp << 2) + (rem & 3);
    bx = rem >> 2;
}

__device__ __forceinline__ void epilogue128(f32x4 acc[4][4], u16* O, const u16* Emul,
                                            int m0, int n0, int N, int mode, bool emul) {
    const int lane = threadIdx.x & 63, wid = threadIdx.x >> 6;
    const int wr = wid >> 1, wc = wid & 1;
    const int r16 = lane & 15, g = lane >> 4;
#pragma unroll
    for (int m = 0; m < 4; ++m)
#pragma unroll
        for (int n = 0; n < 4; ++n)
#pragma unroll
            for (int j = 0; j < 4; ++j) {
                int row = m0 + wr * 64 + m * 16 + g * 4 + j;
                int col = n0 + wc * 64 + n * 16 + r16;
                float v = acc[m][n][j];
                if (mode == 1) v = 1.f / (1.f + expf(-v));
                else if (mode == 2) { v = fmaxf(v, 0.f); v = v * v; }
                size_t o = (size_t)row * N + col;
                if (emul) v *= b2f(Emul[o]);
                O[o] = f2b(v);
            }
}

// ------------------------------------------------ single GEMM (bf16 out), 128x128 tile
template<int MODE, bool EMUL>
__global__ __launch_bounds__(256, 2)
void gemm128(const u16* __restrict__ A, const u16* __restrict__ WT,
             u16* __restrict__ Cout, const u16* __restrict__ Emul, int N, int K) {
    __shared__ u16 L[32768];
    int bx, by;
    xcd_remap2(bx, by);
    const int m0 = by << 7, n0 = bx << 7;
    f32x4 acc[4][4];
#pragma unroll
    for (int i = 0; i < 4; ++i)
#pragma unroll
        for (int j = 0; j < 4; ++j)
#pragma unroll
            for (int q = 0; q < 4; ++q) acc[i][j][q] = 0.f;
    gemm_core128(A, WT, K, m0, n0, L, acc);
    epilogue128(acc, Cout, Emul, m0, n0, N, MODE, EMUL);
}

// ------------------------------------------------ fused K/V/R projections (blockIdx.z = slice)
struct P3 {
    const u16 *A0, *A1, *A2;
    const u16 *W0, *W1, *W2;
    u16 *O0, *O1, *O2;
};
__global__ __launch_bounds__(256, 2)
void proj3(P3 p, int N, int K) {
    __shared__ u16 L[32768];
    const int z = blockIdx.z;
    const u16* A = (z == 0) ? p.A0 : (z == 1) ? p.A1 : p.A2;
    const u16* W = (z == 0) ? p.W0 : (z == 1) ? p.W1 : p.W2;
    u16* O = (z == 0) ? p.O0 : (z == 1) ? p.O1 : p.O2;
    int bx, by;
    xcd_remap2(bx, by);
    const int m0 = by << 7, n0 = bx << 7;
    f32x4 acc[4][4];
#pragma unroll
    for (int i = 0; i < 4; ++i)
#pragma unroll
        for (int j = 0; j < 4; ++j)
#pragma unroll
            for (int q = 0; q < 4; ++q) acc[i][j][q] = 0.f;
    gemm_core128(A, W, K, m0, n0, L, acc);
    epilogue128(acc, O, nullptr, m0, n0, N, (z == 2) ? 1 : 0, false);
}

// ------------------------------------------------ fused FFN1 (relu^2) + Rr (sigmoid)
struct J2 {
    const u16 *A0, *W0; u16 *O0;   // FFN1: N=3072 (24 col-tiles)
    const u16 *A1, *W1; u16 *O1;   // Rr:   N=768  (6 col-tiles)
};
__global__ __launch_bounds__(256, 2)
void ffn1rr(J2 p, int K) {
    __shared__ u16 L[32768];
    int bx, by;
    xcd_remap2(bx, by);
    const bool isF = (bx < 24);
    const u16* A = isF ? p.A0 : p.A1;
    const u16* W = isF ? p.W0 : p.W1;
    u16* O = isF ? p.O0 : p.O1;
    const int N = isF ? 3072 : 768;
    const int m0 = by << 7;
    const int n0 = (isF ? bx : bx - 24) << 7;
    f32x4 acc[4][4];
#pragma unroll
    for (int i = 0; i < 4; ++i)
#pragma unroll
        for (int j = 0; j < 4; ++j)
#pragma unroll
            for (int q = 0; q < 4; ++q) acc[i][j][q] = 0.f;
    gemm_core128(A, W, K, m0, n0, L, acc);
    epilogue128(acc, O, nullptr, m0, n0, N, isF ? 2 : 1, false);
}

// ------------------------------------------------ WKV segmented scan, 2 channels/thread
__global__ void wkv_p1(const float* __restrict__ td, const u16* __restrict__ K,
                       const u16* __restrict__ V, float* __restrict__ st) {
    int idx = blockIdx.x * 256 + threadIdx.x;
    int seg = blockIdx.y;
    int c2 = idx * 2;
    int b = c2 / C_, c = c2 - b * C_;
    float w0 = -expf(td[c]), w1 = -expf(td[c + 1]);
    size_t off = (size_t)b * T_ * C_ + (size_t)seg * WSEG * C_ + c;
    float aa0 = 0.f, bb0 = 0.f, pp0 = -1e38f;
    float aa1 = 0.f, bb1 = 0.f, pp1 = -1e38f;
#pragma unroll 4
    for (int i = 0; i < WSEG; ++i) {
        ushort2 k2 = *(const ushort2*)(K + off + (size_t)i * C_);
        ushort2 v2 = *(const ushort2*)(V + off + (size_t)i * C_);
        {
            float kt = b2f(k2.x), vt = b2f(v2.x);
            float ww = pp0 + w0;
            float p = fmaxf(ww, kt);
            float e1 = expf(ww - p), e2 = expf(kt - p);
            aa0 = e1 * aa0 + e2 * vt; bb0 = e1 * bb0 + e2; pp0 = p;
        }
        {
            float kt = b2f(k2.y), vt = b2f(v2.y);
            float ww = pp1 + w1;
            float p = fmaxf(ww, kt);
            float e1 = expf(ww - p), e2 = expf(kt - p);
            aa1 = e1 * aa1 + e2 * vt; bb1 = e1 * bb1 + e2; pp1 = p;
        }
    }
    int sidx = seg * 3 * BC_ + b * C_ + c;
    *(float2*)(st + sidx) = make_float2(aa0, aa1);
    *(float2*)(st + sidx + BC_) = make_float2(bb0, bb1);
    *(float2*)(st + sidx + 2 * BC_) = make_float2(pp0, pp1);
}

__global__ void wkv_p3(const float* __restrict__ td, const float* __restrict__ tf,
                       const u16* __restrict__ K, const u16* __restrict__ V,
                       const u16* __restrict__ R, const float* __restrict__ st,
                       u16* __restrict__ RY) {
    int idx = blockIdx.x * 256 + threadIdx.x;
    int seg = blockIdx.y;
    int c2 = idx * 2;
    int b = c2 / C_, c = c2 - b * C_;
    float w0 = -expf(td[c]), w1 = -expf(td[c + 1]);
    float u0 = tf[c], u1 = tf[c + 1];
    float wL0 = w0 * (float)WSEG, wL1 = w1 * (float)WSEG;
    float aa0 = 0.f, bb0 = 0.f, pp0 = -1e38f;
    float aa1 = 0.f, bb1 = 0.f, pp1 = -1e38f;
    for (int s = 0; s < seg; ++s) {
        int sidx = s * 3 * BC_ + b * C_ + c;
        float2 la = *(const float2*)(st + sidx);
        float2 lb = *(const float2*)(st + sidx + BC_);
        float2 lp = *(const float2*)(st + sidx + 2 * BC_);
        {
            float ppw = pp0 + wL0;
            float p = fmaxf(ppw, lp.x);
            float e1 = expf(ppw - p), e2 = expf(lp.x - p);
            aa0 = e1 * aa0 + e2 * la.x; bb0 = e1 * bb0 + e2 * lb.x; pp0 = p;
        }
        {
            float ppw = pp1 + wL1;
            float p = fmaxf(ppw, lp.y);
            float e1 = expf(ppw - p), e2 = expf(lp.y - p);
            aa1 = e1 * aa1 + e2 * la.y; bb1 = e1 * bb1 + e2 * lb.y; pp1 = p;
        }
    }
    size_t off = (size_t)b * T_ * C_ + (size_t)seg * WSEG * C_ + c;
#pragma unroll 4
    for (int i = 0; i < WSEG; ++i) {
        ushort2 k2 = *(const ushort2*)(K + off + (size_t)i * C_);
        ushort2 v2 = *(const ushort2*)(V + off + (size_t)i * C_);
        ushort2 r2 = *(const ushort2*)(R + off + (size_t)i * C_);
        ushort2 o2v;
        {
            float kt = b2f(k2.x), vt = b2f(v2.x), rr = b2f(r2.x);
            float ww = u0 + kt;
            float p = fmaxf(pp0, ww);
            float e1 = expf(pp0 - p), e2 = expf(ww - p);
            o2v.x = f2b(rr * (e1 * aa0 + e2 * vt) / (e1 * bb0 + e2));
            float ww2 = pp0 + w0;
            float p2 = fmaxf(ww2, kt);
            float e1b = expf(ww2 - p2), e2b = expf(kt - p2);
            aa0 = e1b * aa0 + e2b * vt; bb0 = e1b * bb0 + e2b; pp0 = p2;
        }
        {
            float kt = b2f(k2.y), vt = b2f(v2.y), rr = b2f(r2.y);
            float ww = u1 + kt;
            float p = fmaxf(pp1, ww);
            float e1 = expf(pp1 - p), e2 = expf(ww - p);
            o2v.y = f2b(rr * (e1 * aa1 + e2 * vt) / (e1 * bb1 + e2));
            float ww2 = pp1 + w1;
            float p2 = fmaxf(ww2, kt);
            float e1b = expf(ww2 - p2), e2b = expf(kt - p2);
            aa1 = e1b * aa1 + e2b * vt; bb1 = e1b * bb1 + e2b; pp1 = p2;
        }
        *(ushort2*)(RY + off + (size_t)i * C_) = o2v;
    }
}

// ------------------------------------------------ LIF + residual, 2 channels/thread
__global__ void lif_add_b(const u16* __restrict__ cur, const float* __restrict__ base,
                          float* __restrict__ out) {
    int idx = blockIdx.x * 256 + threadIdx.x;
    int seg = blockIdx.y;
    int c2 = idx * 2;
    int b = c2 / C_, c = c2 - b * C_;
    size_t rowbase = (size_t)b * T_ * C_ + c;
    int t0 = seg * LSEG;
    int tw = t0 - LWARM; if (tw < 0) tw = 0;
    int nw = t0 - tw;
    float v0 = 0.f, v1 = 0.f;
    const u16* cp = cur + rowbase + (size_t)tw * C_;
#pragma unroll 8
    for (int i = 0; i < nw; ++i) {
        ushort2 x2 = *(const ushort2*)(cp + (size_t)i * C_);
        v0 += (b2f(x2.x) - v0) * 0.5f;
        v0 = (v0 >= 1.f) ? 0.f : v0;
        v1 += (b2f(x2.y) - v1) * 0.5f;
        v1 = (v1 >= 1.f) ? 0.f : v1;
    }
    const u16* cq = cur + rowbase + (size_t)t0 * C_;
    const float* bp = base + rowbase + (size_t)t0 * C_;
    float* op = out + rowbase + (size_t)t0 * C_;
#pragma unroll 8
    for (int i = 0; i < LSEG; ++i) {
        ushort2 x2 = *(const ushort2*)(cq + (size_t)i * C_);
        float2 b2 = *(const float2*)(bp + (size_t)i * C_);
        v0 += (b2f(x2.x) - v0) * 0.5f;
        float s0 = (v0 >= 1.f) ? 1.f : 0.f;
        v1 += (b2f(x2.y) - v1) * 0.5f;
        float s1 = (v1 >= 1.f) ? 1.f : 0.f;
        *(float2*)(op + (size_t)i * C_) = make_float2(b2.x + s0, b2.y + s1);
        v0 = (s0 > 0.f) ? 0.f : v0;
        v1 = (s1 > 0.f) ? 0.f : v1;
    }
}

// ------------------------------------------------ launcher
extern "C" void kernel_launch(void* const* d_in, const int* in_sizes, int n_in,
                              void* d_out, int out_size, void* d_ws, size_t ws_size,
                              hipStream_t stream) {
    const float* x    = (const float*)d_in[0];
    const float* ln1w = (const float*)d_in[1];
    const float* ln1b = (const float*)d_in[2];
    const float* ln2w = (const float*)d_in[3];
    const float* ln2b = (const float*)d_in[4];
    const float* td   = (const float*)d_in[5];
    const float* tf   = (const float*)d_in[6];
    const float* amk  = (const float*)d_in[7];
    const float* amv  = (const float*)d_in[8];
    const float* amr  = (const float*)d_in[9];
    const float* aWk  = (const float*)d_in[10];
    const float* aWv  = (const float*)d_in[11];
    const float* aWr  = (const float*)d_in[12];
    const float* aWo  = (const float*)d_in[13];
    const float* fmk  = (const float*)d_in[14];
    const float* fmr  = (const float*)d_in[15];
    const float* fWk  = (const float*)d_in[16];
    const float* fWv  = (const float*)d_in[17];
    const float* fWr  = (const float*)d_in[18];
    float* out = (float*)d_out;

    const size_t NBC = (size_t)BT_ * C_;
    u16* WkT = (u16*)d_ws;
    u16* WvT = WkT + 589824;
    u16* WrT = WvT + 589824;
    u16* WoT = WrT + 589824;
    u16* FrT = WoT + 589824;
    u16* FkT = FrT + 589824;                  // [3072][768]
    u16* FvT = FkT + 2359296;                 // [768][3072]
    float* st  = (float*)(FvT + 2359296);
    u16* S0 = (u16*)(st + NWSEG * 3 * BC_);
    u16* S1 = S0 + NBC;
    u16* S2 = S1 + NBC;
    u16* S3 = S2 + NBC;
    u16* Hbuf = S3 + NBC;
    size_t fixed_b = (size_t)((char*)Hbuf - (char*)d_ws);

    int NCH = 4;
    if (ws_size >= fixed_b + ((size_t)BT_ * H_ + NBC) * 2) NCH = 1;
    else if (ws_size >= fixed_b + ((size_t)(BT_ / 2) * H_ + NBC / 2) * 2) NCH = 2;
    const int CH = BT_ / NCH;
    u16* Fbuf = Hbuf + (size_t)CH * H_;

    u16* Kb = (u16*)d_out;
    u16* Vb = Kb + NBC;

    // 0. weights -> bf16 [N][K]
    {
        TC7 jobs;
        const float* srcs[7] = {aWk, aWv, aWr, aWo, fWr, fWk, fWv};
        u16* dsts[7] = {WkT, WvT, WrT, WoT, FrT, FkT, FvT};
        int Rs[7]    = {768, 768, 768, 768, 768, 768, 3072};
        int Ns[7]    = {768, 768, 768, 768, 768, 3072, 768};
        int b0 = 0;
        for (int k = 0; k < 7; ++k) {
            jobs.j[k].s = srcs[k]; jobs.j[k].d = dsts[k];
            jobs.j[k].R = Rs[k]; jobs.j[k].Ncol = Ns[k];
            jobs.j[k].nbx = Ns[k] / 32; jobs.j[k].b0 = b0;
            b0 += (Ns[k] / 32) * (Rs[k] / 32);
        }
        tcast_all<<<b0, 256, 0, stream>>>(jobs);
    }

    // 1. xk,xv,xr = mix(ln1(x)) -> S0,S1,S2
    lnmixw<3><<<BT_ / 8, 512, 0, stream>>>(x, ln1w, ln1b, amk, amv, amr, S0, S1, S2);
    // 2. K,V,sigmoid(R)
    {
        P3 p{S0, S1, S2, WkT, WvT, WrT, Kb, Vb, S3};
        proj3<<<dim3(6, 128, 3), 256, 0, stream>>>(p, C_, C_);
    }
    // 3. RY = sigmoid(R) * wkv(K,V) -> S0
    wkv_p1<<<dim3(BC_ / 512, NWSEG), 256, 0, stream>>>(td, Kb, Vb, st);
    wkv_p3<<<dim3(BC_ / 512, NWSEG), 256, 0, stream>>>(td, tf, Kb, Vb, S3, st, S0);
    // 4. A_out = RY @ Wo -> bf16 S1
    gemm128<0, false><<<dim3(6, 128), 256, 0, stream>>>(S0, WoT, S1, nullptr, C_, C_);
    // 5. X2 = x + lif(A_out) -> d_out
    lif_add_b<<<dim3(BC_ / 512, NLSEG), 256, 0, stream>>>(S1, x, out);
    // 6. xk2 -> S0, xr2 -> S1
    lnmixw<2><<<BT_ / 8, 512, 0, stream>>>(out, ln2w, ln2b, fmk, fmr, nullptr, S0, S1, nullptr);

    if (NCH == 1) {
        J2 p{S0, FkT, Hbuf, S1, FrT, S2};
        ffn1rr<<<dim3(30, 128), 256, 0, stream>>>(p, C_);
        gemm128<0, true><<<dim3(6, 128), 256, 0, stream>>>(Hbuf, FvT, Fbuf, S2, C_, H_);
        lif_add_b<<<dim3(BC_ / 512, NLSEG), 256, 0, stream>>>(Fbuf, out, out);
    } else {
        gemm128<1, false><<<dim3(6, 128), 256, 0, stream>>>(S1, FrT, S2, nullptr, C_, C_);
        for (int ch = 0; ch < NCH; ++ch) {
            const u16* xk2c = S0 + (size_t)ch * CH * C_;
            const u16* rrc  = S2 + (size_t)ch * CH * C_;
            gemm128<2, false><<<dim3(24, CH / 128), 256, 0, stream>>>(xk2c, FkT, Hbuf, nullptr, H_, C_);
            gemm128<0, true><<<dim3(6, CH / 128), 256, 0, stream>>>(Hbuf, FvT, Fbuf, rrc, C_, H_);
            lif_add_b<<<dim3((CH / T_) * C_ / 512, NLSEG), 256, 0, stream>>>(
                Fbuf, out + (size_t)ch * CH * C_, out + (size_t)ch * CH * C_);
        }
    }
}